// Round 1
// baseline (98.622 us; speedup 1.0000x reference)
//
#include <hip/hip_runtime.h>
#include <math.h>

#define N_IMG 512
#define N_ANGLES 25
#define N_DET 512
#define DET_SPACING 3.0f
#define SRC_DIST 512.0f
#define DET_DIST 512.0f
#define N_SAMPLES 1024

// Bilinear gather with zero-outside semantics matching the reference:
// per-corner validity, clamp-then-load, zero if out of bounds.
__device__ __forceinline__ float gather(const float* __restrict__ img, int r, int c) {
    bool valid = (r >= 0) & (r < N_IMG) & (c >= 0) & (c < N_IMG);
    int rc = min(max(r, 0), N_IMG - 1);
    int cc = min(max(c, 0), N_IMG - 1);
    float v = img[(rc << 9) + cc];
    return valid ? v : 0.0f;
}

__global__ __launch_bounds__(256) void fanbeam_kernel(const float* __restrict__ img,
                                                      float* __restrict__ out) {
    const int gid  = blockIdx.x * blockDim.x + threadIdx.x;
    const int ray  = gid >> 6;          // one wave64 per ray
    const int lane = threadIdx.x & 63;
    if (ray >= N_ANGLES * N_DET) return;

    const int a = ray / N_DET;
    const int d = ray - a * N_DET;

    // Per-ray geometry (once per wave; double trig for accuracy, cast to f32)
    double beta = (2.0 * M_PI) * (double)a / (double)N_ANGLES;
    float c = (float)cos(beta);
    float s = (float)sin(beta);
    float t = ((float)d - (N_DET - 1) * 0.5f) * DET_SPACING;
    float srcx = -SRC_DIST * s;
    float srcy =  SRC_DIST * c;
    float detx = t * c + DET_DIST * s;
    float dety = t * s - DET_DIST * c;
    float dx = detx - srcx;
    float dy = dety - srcy;
    float seg = sqrtf(dx * dx + dy * dy);

    const float half = (N_IMG - 1) * 0.5f;   // 255.5
    float acc = 0.0f;

    // Lane-strided: each iteration the wave's 64 lanes sample 64 consecutive
    // points (~64 consecutive pixels along the ray) — good cache locality.
    for (int i = lane; i < N_SAMPLES; i += 64) {
        float ts  = ((float)i + 0.5f) * (1.0f / N_SAMPLES);
        float col = fmaf(ts, dx, srcx) + half;
        float row = half - fmaf(ts, dy, srcy);
        float r0 = floorf(row), c0 = floorf(col);
        float fr = row - r0,    fc = col - c0;
        int r0i = (int)r0, c0i = (int)c0;
        float v00 = gather(img, r0i,     c0i);
        float v01 = gather(img, r0i,     c0i + 1);
        float v10 = gather(img, r0i + 1, c0i);
        float v11 = gather(img, r0i + 1, c0i + 1);
        acc += (v00 * (1.0f - fr) + v10 * fr) * (1.0f - fc)
             + (v01 * (1.0f - fr) + v11 * fr) * fc;
    }

    // wave64 shuffle reduction
    #pragma unroll
    for (int off = 32; off > 0; off >>= 1)
        acc += __shfl_down(acc, off, 64);

    if (lane == 0) out[ray] = acc * (seg * (1.0f / N_SAMPLES));
}

extern "C" void kernel_launch(void* const* d_in, const int* in_sizes, int n_in,
                              void* d_out, int out_size, void* d_ws, size_t ws_size,
                              hipStream_t stream) {
    const float* img = (const float*)d_in[0];
    float* out = (float*)d_out;
    const int n_rays = N_ANGLES * N_DET;              // 12800
    const int threads = 256;                          // 4 waves = 4 rays / block
    const int blocks = (n_rays * 64 + threads - 1) / threads;  // 3200
    fanbeam_kernel<<<blocks, threads, 0, stream>>>(img, out);
}

// Round 2
// 75.115 us; speedup vs baseline: 1.3129x; 1.3129x over previous
//
#include <hip/hip_runtime.h>
#include <math.h>

#define N_IMG 512
#define N_ANGLES 25
#define N_DET 512
#define DET_SPACING 3.0f
#define SRC_DIST 512.0f
#define DET_DIST 512.0f
#define N_SAMPLES 1024

// ---------------------------------------------------------------------------
// Pre-pass: pack each pixel's 2x2 bilinear footprint into one float4 so the
// main kernel does ONE dwordx4 gather per interior sample instead of four
// scattered dword gathers.  quad[r][c] = {img[r][c], img[r][c+1],
//                                         img[r+1][c], img[r+1][c+1]}
// (edges clamped; interior fast path only ever reads r,c <= 510).
// ---------------------------------------------------------------------------
__global__ __launch_bounds__(256) void build_quads(const float* __restrict__ img,
                                                   float4* __restrict__ quad) {
    int idx = blockIdx.x * blockDim.x + threadIdx.x;   // 0 .. 512*512-1
    int r = idx >> 9, c = idx & 511;
    int c1 = min(c + 1, N_IMG - 1);
    int r1 = min(r + 1, N_IMG - 1);
    float4 q;
    q.x = img[(r  << 9) + c ];
    q.y = img[(r  << 9) + c1];
    q.z = img[(r1 << 9) + c ];
    q.w = img[(r1 << 9) + c1];
    quad[idx] = q;
}

// Reference-exact masked bilinear sample against the original image.
__device__ __forceinline__ float masked_sample(const float* __restrict__ img,
                                               float col, float row) {
    float rf = floorf(row), cf = floorf(col);
    float fr = row - rf,    fc = col - cf;
    int r0 = (int)rf, c0 = (int)cf;
    float wr0 = (r0 >=  0 && r0 < N_IMG)     ? (1.0f - fr) : 0.0f;
    float wr1 = (r0 >= -1 && r0 < N_IMG - 1) ? fr          : 0.0f;
    float wc0 = (c0 >=  0 && c0 < N_IMG)     ? (1.0f - fc) : 0.0f;
    float wc1 = (c0 >= -1 && c0 < N_IMG - 1) ? fc          : 0.0f;
    int rc0 = min(max(r0,     0), N_IMG - 1);
    int rc1 = min(max(r0 + 1, 0), N_IMG - 1);
    int cc0 = min(max(c0,     0), N_IMG - 1);
    int cc1 = min(max(c0 + 1, 0), N_IMG - 1);
    float v00 = img[(rc0 << 9) + cc0];
    float v01 = img[(rc0 << 9) + cc1];
    float v10 = img[(rc1 << 9) + cc0];
    float v11 = img[(rc1 << 9) + cc1];
    return wr0 * (wc0 * v00 + wc1 * v01) + wr1 * (wc0 * v10 + wc1 * v11);
}

// Clip [tlo,thi] to { t : lo <= v0 + t*dv <= hi }.
__device__ __forceinline__ void slab(float v0, float dv, float lo, float hi,
                                     float& tlo, float& thi) {
    if (fabsf(dv) < 1e-8f) {
        if (v0 < lo || v0 > hi) { tlo = 1.0f; thi = 0.0f; }   // empty
    } else {
        float inv = 1.0f / dv;
        float ta = (lo - v0) * inv;
        float tb = (hi - v0) * inv;
        tlo = fmaxf(tlo, fminf(ta, tb));
        thi = fminf(thi, fmaxf(ta, tb));
    }
}

__global__ __launch_bounds__(256) void fanbeam_kernel(const float* __restrict__ img,
                                                      const float4* __restrict__ quad,
                                                      float* __restrict__ out) {
    const int gid  = blockIdx.x * blockDim.x + threadIdx.x;
    const int ray  = gid >> 6;          // one wave64 per ray
    const int lane = threadIdx.x & 63;
    if (ray >= N_ANGLES * N_DET) return;

    const int a = ray / N_DET;
    const int d = ray - a * N_DET;

    double beta = (2.0 * M_PI) * (double)a / (double)N_ANGLES;
    float c = (float)cos(beta);
    float s = (float)sin(beta);
    float t = ((float)d - (N_DET - 1) * 0.5f) * DET_SPACING;
    float srcx = -SRC_DIST * s;
    float srcy =  SRC_DIST * c;
    float dx = (t * c + DET_DIST * s) - srcx;
    float dy = (t * s - DET_DIST * c) - srcy;
    float seg = sqrtf(dx * dx + dy * dy);

    const float half = (N_IMG - 1) * 0.5f;   // 255.5
    // col(ts) = col0 + ts*dx ; row(ts) = row0 + ts*drow
    const float col0 = srcx + half;
    const float row0 = half - srcy;
    const float drow = -dy;
    const float inv_n = 1.0f / N_SAMPLES;

    // Outer window: beyond col/row in [-1, 512] every corner is invalid -> 0.
    float tA = 0.0f, tB = 1.0f;
    slab(col0, dx,   -1.01f, 512.01f, tA, tB);
    slab(row0, drow, -1.01f, 512.01f, tA, tB);
    int i_lo, i_hi;
    if (tB < tA) { i_lo = 1; i_hi = 0; }
    else {
        i_lo = max(0,             (int)floorf(tA * N_SAMPLES - 0.5f) - 1);
        i_hi = min(N_SAMPLES - 1, (int)ceilf (tB * N_SAMPLES - 0.5f) + 1);
    }

    // Interior window: col,row in [0.01, 510.99] => all four corners valid,
    // indices in [0,510]; clamps below are a never-binding safety net.
    float tC = 0.0f, tD = 1.0f;
    slab(col0, dx,   0.01f, 510.99f, tC, tD);
    slab(row0, drow, 0.01f, 510.99f, tC, tD);
    int j_lo, j_hi;
    if (tD < tC) { j_lo = 1; j_hi = 0; }
    else {
        j_lo = (int)ceilf (tC * N_SAMPLES - 0.5f) + 1;
        j_hi = (int)floorf(tD * N_SAMPLES - 0.5f) - 1;
    }
    j_lo = max(j_lo, i_lo);
    j_hi = min(j_hi, i_hi);

    float acc = 0.0f;

    if (j_lo > j_hi) {
        // No interior stretch: masked path over the whole window.
        for (int i = i_lo + lane; i <= i_hi; i += 64) {
            float ts  = ((float)i + 0.5f) * inv_n;
            acc += masked_sample(img, fmaf(ts, dx, col0), fmaf(ts, drow, row0));
        }
    } else {
        // Leading boundary band (typically <= ~3 samples/lane).
        for (int i = i_lo + lane; i < j_lo; i += 64) {
            float ts  = ((float)i + 0.5f) * inv_n;
            acc += masked_sample(img, fmaf(ts, dx, col0), fmaf(ts, drow, row0));
        }
        // Interior fast path: ONE dwordx4 gather per sample, no masks.
        #pragma unroll 2
        for (int i = j_lo + lane; i <= j_hi; i += 64) {
            float ts  = ((float)i + 0.5f) * inv_n;
            float col = fmaf(ts, dx,   col0);
            float row = fmaf(ts, drow, row0);
            float cf = floorf(col), rf = floorf(row);
            float fc = col - cf,    fr = row - rf;
            int ci = min(max((int)cf, 0), N_IMG - 2);
            int ri = min(max((int)rf, 0), N_IMG - 2);
            float4 q = quad[(ri << 9) + ci];
            float top = fmaf(fc, q.y - q.x, q.x);
            float bot = fmaf(fc, q.w - q.z, q.z);
            acc += fmaf(fr, bot - top, top);
        }
        // Trailing boundary band.
        for (int i = max(j_hi + 1, i_lo) + lane; i <= i_hi; i += 64) {
            float ts  = ((float)i + 0.5f) * inv_n;
            acc += masked_sample(img, fmaf(ts, dx, col0), fmaf(ts, drow, row0));
        }
    }

    #pragma unroll
    for (int off = 32; off > 0; off >>= 1)
        acc += __shfl_down(acc, off, 64);

    if (lane == 0) out[ray] = acc * (seg * inv_n);
}

extern "C" void kernel_launch(void* const* d_in, const int* in_sizes, int n_in,
                              void* d_out, int out_size, void* d_ws, size_t ws_size,
                              hipStream_t stream) {
    const float* img = (const float*)d_in[0];
    float4* quad = (float4*)d_ws;                     // 512*512*16 B = 4 MB
    float* out = (float*)d_out;

    build_quads<<<(N_IMG * N_IMG) / 256, 256, 0, stream>>>(img, quad);

    const int n_rays = N_ANGLES * N_DET;              // 12800
    const int threads = 256;                          // 4 waves = 4 rays / block
    const int blocks = (n_rays * 64 + threads - 1) / threads;  // 3200
    fanbeam_kernel<<<blocks, threads, 0, stream>>>(img, quad, out);
}